// Round 8
// baseline (190.210 us; speedup 1.0000x reference)
//
#include <hip/hip_runtime.h>

// RaggedAttention on MI355X — bf16 MFMA pipeline.
// XP bf16[32768][256]; WCAT bf16[768][256] ([f][c] = B^T input);
// QKVp bf16[32768][768]; Y bf16[32768][256].
// MFMA 16x16x32_bf16 mappings (HW-verified per guide):
//   A-frag: lane holds A[m=lane&15][k=(lane>>4)*8+j]
//   B-frag: lane holds B[k=(lane>>4)*8+j][n=lane&15]
//   C/D   : lane reg r holds D[row=(lane>>4)*4+r][col=lane&15]
// r7: swapped QK^T + permlane swaps rebuild PV A-frag in-register (pscr gone).
// r10: half-block split REGRESSED (occupancy was not the constraint).
// r11: VSP 530 bank fix = noise (conflicts off critical path).
// r12 (this round): attn is dependency-LATENCY bound: ~1540 cyc/s-iter vs
// ~400 MFMA + ~650 VALU issue. The 4 per-mt `asm volatile` swap blocks were
// compiler-ordered -> 4 serial chains of (MFMA-lat + exp-lat + swap-lat).
// Phase-batched iteration: [all 8 ST MFMAs] -> [all mask/exp/pack VALU] ->
// [ONE fused 16-operand swap asm block] -> [setprio(1) PV MFMA cluster].

typedef __attribute__((ext_vector_type(8))) short short8;
typedef __attribute__((ext_vector_type(4))) float f32x4;

#define N_TOTAL 24576
#define B_ 64
#define T_ 512
#define DM 256
#define NH 8
#define HD 32
#define F3 768

// log2(e)/sqrt(HD) — folded into Q at projection time
#define QSCALE 0.25503463f
#define VSP 530   // LDS V-tile row stride (shorts): dword-stride 265 = 9 mod 32

__device__ __forceinline__ unsigned short f2bf(float f) {
  unsigned int u = __float_as_uint(f);
  u += 0x7fffu + ((u >> 16) & 1u);   // RNE
  return (unsigned short)(u >> 16);
}

__device__ __forceinline__ void gl_lds16(const void* g, void* l) {
  __builtin_amdgcn_global_load_lds(
      (const __attribute__((address_space(1))) unsigned int*)g,
      (__attribute__((address_space(3))) unsigned int*)l, 16, 0, 0);
}

// ---------------- kernel 0: gather + bf16 cast + weight packing ----------------
__global__ __launch_bounds__(256) void pack_kernel(
    const float* __restrict__ x, const float* __restrict__ Wq,
    const float* __restrict__ Wk, const float* __restrict__ Wv,
    const float* __restrict__ Wp, const float* __restrict__ bq,
    const float* __restrict__ bk, const float* __restrict__ bv,
    const int* __restrict__ idx,
    short* __restrict__ XP, short* __restrict__ WCAT, short* __restrict__ WPb,
    float* __restrict__ BCAT) {
  int gid = blockIdx.x * 256 + threadIdx.x;
  if (gid < 768)
    BCAT[gid] = (gid < 256) ? bq[gid] : (gid < 512 ? bk[gid - 256] : bv[gid - 512]);
  const float* src;
  short* dst;
  if (gid < 1048576) {
    int row = gid >> 5, seg = gid & 31;
    src = x + (size_t)idx[row] * DM + seg * 8;
    dst = XP + (size_t)gid * 8;
  } else if (gid < 1073152) {
    int u = gid - 1048576;
    int f = u >> 5, seg = u & 31;
    const float* W = (f < 256) ? Wq : ((f < 512) ? Wk : Wv);
    src = W + (size_t)(f & 255) * DM + seg * 8;
    dst = WCAT + (size_t)u * 8;
  } else {
    int u = gid - 1073152;
    src = Wp + (size_t)u * 8;
    dst = WPb + (size_t)u * 8;
  }
  const float4* s4 = (const float4*)src;
  float4 a = s4[0], b = s4[1];
  short8 o;
  o[0] = (short)f2bf(a.x); o[1] = (short)f2bf(a.y);
  o[2] = (short)f2bf(a.z); o[3] = (short)f2bf(a.w);
  o[4] = (short)f2bf(b.x); o[5] = (short)f2bf(b.y);
  o[6] = (short)f2bf(b.z); o[7] = (short)f2bf(b.w);
  *(short8*)dst = o;
}

// ---------------- kernel 1: QKV GEMM (M=32768,N=768,K=256) --------------------
__global__ __launch_bounds__(256) void qkv_gemm(
    const short* __restrict__ XP, const short* __restrict__ WCAT,
    const float* __restrict__ BCAT, unsigned short* __restrict__ QKVp) {
  __shared__ __align__(16) char smem[3 * 16384];
  int tid = threadIdx.x;
  int lane = tid & 63, w = tid >> 6;
  int i = lane & 15, q = lane >> 4;
  int m0 = blockIdx.x * 128, n0 = blockIdx.y * 128;
  int wm = (w & 1) * 64, wn = (w >> 1) * 64;
  int csa = q ^ ((i >> 1) & 3);

  f32x4 zf = {0.f, 0.f, 0.f, 0.f};
  f32x4 acc[4][4];
#pragma unroll
  for (int mt = 0; mt < 4; mt++)
#pragma unroll
    for (int nt = 0; nt < 4; nt++) acc[mt][nt] = zf;

  auto stage = [&](int k, int s) {
#pragma unroll
    for (int p = 0; p < 2; p++) {
      int U = p * 256 + tid;
      int row = U >> 2, c = U & 3;
      int cs = c ^ ((row >> 1) & 3);
      gl_lds16(XP + (size_t)(m0 + row) * DM + k * 32 + cs * 8,
               smem + s * 16384 + U * 16);
      gl_lds16(WCAT + (size_t)(n0 + row) * DM + k * 32 + cs * 8,
               smem + s * 16384 + 8192 + U * 16);
    }
  };

  stage(0, 0);
  stage(1, 1);
#pragma unroll
  for (int k = 0; k < 8; k++) {
    if (k == 7)
      asm volatile("s_waitcnt vmcnt(0) lgkmcnt(0)\ns_barrier" ::: "memory");
    else
      asm volatile("s_waitcnt vmcnt(4) lgkmcnt(0)\ns_barrier" ::: "memory");
    const short* Asb = (const short*)(smem + (k % 3) * 16384);
    const short* Bsb = Asb + 4096;
    short8 a[4], bfr[4];
#pragma unroll
    for (int mt = 0; mt < 4; mt++)
      a[mt] = *(const short8*)&Asb[(wm + mt * 16 + i) * 32 + csa * 8];
#pragma unroll
    for (int nt = 0; nt < 4; nt++)
      bfr[nt] = *(const short8*)&Bsb[(wn + nt * 16 + i) * 32 + csa * 8];
    if (k < 6) stage(k + 2, (k + 2) % 3);
#pragma unroll
    for (int mt = 0; mt < 4; mt++)
#pragma unroll
      for (int nt = 0; nt < 4; nt++)
        acc[mt][nt] = __builtin_amdgcn_mfma_f32_16x16x32_bf16(a[mt], bfr[nt], acc[mt][nt], 0, 0, 0);
  }

  // epilogue: bias (+QSCALE for Q-part) and store to unified QKVp[token][f].
  float scale = (n0 < 256) ? QSCALE : 1.0f;
#pragma unroll
  for (int nt = 0; nt < 4; nt++) {
    int f = n0 + wn + nt * 16 + i;
    float bias = BCAT[f];
#pragma unroll
    for (int mt = 0; mt < 4; mt++) {
#pragma unroll
      for (int r = 0; r < 4; r++) {
        int token = m0 + wm + mt * 16 + q * 4 + r;
        QKVp[(size_t)token * F3 + f] = f2bf((acc[mt][nt][r] + bias) * scale);
      }
    }
  }
}

// ---------------- kernel 2: attention ----------------
// block = 8 waves (512 thr); wave = 64 t-rows of one (b,h); s-step 32.
// Grid 512 = one block per (b,h): 2 blocks/CU, no tail; h = bx>>6, b = bx&63.
// Phase-batched s-iteration (r12): 8 ST MFMAs -> mask/exp/pack VALU (all mt)
// -> ONE fused 16-operand permlane swap block -> setprio'd PV MFMA cluster.
__global__ __launch_bounds__(512, 4) void attn_kernel(
    const unsigned short* __restrict__ QKVp, const int* __restrict__ batch,
    unsigned short* __restrict__ Y) {
  __shared__ __align__(16) short Vl[HD * VSP];      // 33,920 B
  __shared__ int sbat[T_];                          //  2,048 B
  int tid = threadIdx.x, w = tid >> 6, lane = tid & 63;
  int i = lane & 15, q = lane >> 4;
  int bx = blockIdx.x;
  int h = bx >> 6, b = bx & 63;   // all 8 heads of a batch share an XCD
  int t0 = w * 64;
  const unsigned short* Tok = QKVp + (size_t)b * T_ * F3;  // this batch's rows

  sbat[tid] = batch[b * T_ + tid];

  // V transpose: global [t][d] (64B head-aligned lines) -> LDS Vl[d][s]
  {
    int seg = tid & 3, sb = tid >> 2;   // seg: 8-d chunk; sb: s base (0..127)
#pragma unroll
    for (int l = 0; l < 4; l++) {
      int s = sb + l * 128;
      short8 v = *(const short8*)&Tok[(size_t)s * F3 + 512 + h * HD + seg * 8];
#pragma unroll
      for (int j = 0; j < 8; j++) Vl[(seg * 8 + j) * VSP + s] = v[j];
    }
  }
  __syncthreads();

  short8 qf[4];
  int btm[4];
#pragma unroll
  for (int mt = 0; mt < 4; mt++)
    qf[mt] = *(const short8*)&Tok[(size_t)(t0 + mt * 16 + i) * F3 + h * HD + q * 8];
#pragma unroll
  for (int mt = 0; mt < 4; mt++) btm[mt] = sbat[t0 + mt * 16 + i];

  // ones B-fragment: B[k][n] = (n==0) ? 1.0bf16 : 0
  unsigned short ob = (i == 0) ? (unsigned short)0x3F80 : (unsigned short)0;
  short8 ones = {(short)ob, (short)ob, (short)ob, (short)ob,
                 (short)ob, (short)ob, (short)ob, (short)ob};

  f32x4 zf = {0.f, 0.f, 0.f, 0.f};
  f32x4 o[4][2], lacc[4];
#pragma unroll
  for (int mt = 0; mt < 4; mt++) {
    o[mt][0] = zf; o[mt][1] = zf; lacc[mt] = zf;
  }

  // K A-frag: lane (i,q) holds K[s0 + i (+16 for tile1)][d = q*8..q*8+7]
  const unsigned short* Kb = Tok + 256 + h * HD + q * 8;
  short8 k0f = *(const short8*)&Kb[(size_t)(i)*F3];
  short8 k1f = *(const short8*)&Kb[(size_t)(16 + i) * F3];

  for (int s0 = 0; s0 < T_; s0 += 32) {
    short8 ck0 = k0f, ck1 = k1f;
    if (s0 + 32 < T_) {
      k0f = *(const short8*)&Kb[(size_t)(s0 + 32 + i) * F3];
      k1f = *(const short8*)&Kb[(size_t)(s0 + 48 + i) * F3];
    }
    int4 bs0 = *(const int4*)&sbat[s0 + q * 4];        // batch of s = s0+q*4+r
    int4 bs1 = *(const int4*)&sbat[s0 + 16 + q * 4];   // batch of s = s0+16+q*4+r
    short8 v0f = *(const short8*)&Vl[i * VSP + s0 + q * 8];
    short8 v1f = *(const short8*)&Vl[(16 + i) * VSP + s0 + q * 8];

    // ---- phase 1: all 8 QK^T MFMAs (latencies overlap) ----
    f32x4 st[4][2];
#pragma unroll
    for (int mt = 0; mt < 4; mt++) {
      st[mt][0] = __builtin_amdgcn_mfma_f32_16x16x32_bf16(ck0, qf[mt], zf, 0, 0, 0);
      st[mt][1] = __builtin_amdgcn_mfma_f32_16x16x32_bf16(ck1, qf[mt], zf, 0, 0, 0);
    }

    // ---- phase 2: mask + exp + bf16-pack for all mt (independent VALU) ----
    unsigned P[4][4];
#pragma unroll
    for (int mt = 0; mt < 4; mt++) {
      int bm = btm[mt];
      float e00 = __builtin_amdgcn_exp2f((bs0.x == bm) ? -1e9f : st[mt][0][0]);
      float e01 = __builtin_amdgcn_exp2f((bs0.y == bm) ? -1e9f : st[mt][0][1]);
      float e02 = __builtin_amdgcn_exp2f((bs0.z == bm) ? -1e9f : st[mt][0][2]);
      float e03 = __builtin_amdgcn_exp2f((bs0.w == bm) ? -1e9f : st[mt][0][3]);
      float e10 = __builtin_amdgcn_exp2f((bs1.x == bm) ? -1e9f : st[mt][1][0]);
      float e11 = __builtin_amdgcn_exp2f((bs1.y == bm) ? -1e9f : st[mt][1][1]);
      float e12 = __builtin_amdgcn_exp2f((bs1.z == bm) ? -1e9f : st[mt][1][2]);
      float e13 = __builtin_amdgcn_exp2f((bs1.w == bm) ? -1e9f : st[mt][1][3]);
      P[mt][0] = __builtin_amdgcn_perm(__float_as_uint(e01), __float_as_uint(e00), 0x07060302u);
      P[mt][1] = __builtin_amdgcn_perm(__float_as_uint(e03), __float_as_uint(e02), 0x07060302u);
      P[mt][2] = __builtin_amdgcn_perm(__float_as_uint(e11), __float_as_uint(e10), 0x07060302u);
      P[mt][3] = __builtin_amdgcn_perm(__float_as_uint(e13), __float_as_uint(e12), 0x07060302u);
    }

    // ---- phase 3: ONE fused swap block (8x swap32 then 8x swap16).
    // swap32(A,B) -> A=[A.lo|B.lo], B=[A.hi|B.hi]
    // swap16(A,B) -> A=[A.r0,B.r0,A.r2,B.r2], B=[A.r1,B.r1,A.r3,B.r3]
    // 8-instruction spacing covers the swap32->swap16 hazards; s_nop at
    // boundaries covers VALU->swap and swap->MFMA (hazard recognizer is
    // blind inside INLINEASM).
    asm volatile(
        "s_nop 1\n\t"
        "v_permlane32_swap_b32 %0, %2\n\t"
        "v_permlane32_swap_b32 %1, %3\n\t"
        "v_permlane32_swap_b32 %4, %6\n\t"
        "v_permlane32_swap_b32 %5, %7\n\t"
        "v_permlane32_swap_b32 %8, %10\n\t"
        "v_permlane32_swap_b32 %9, %11\n\t"
        "v_permlane32_swap_b32 %12, %14\n\t"
        "v_permlane32_swap_b32 %13, %15\n\t"
        "s_nop 1\n\t"
        "v_permlane16_swap_b32 %0, %2\n\t"
        "v_permlane16_swap_b32 %1, %3\n\t"
        "v_permlane16_swap_b32 %4, %6\n\t"
        "v_permlane16_swap_b32 %5, %7\n\t"
        "v_permlane16_swap_b32 %8, %10\n\t"
        "v_permlane16_swap_b32 %9, %11\n\t"
        "v_permlane16_swap_b32 %12, %14\n\t"
        "v_permlane16_swap_b32 %13, %15\n\t"
        "s_nop 1"
        : "+v"(P[0][0]), "+v"(P[0][1]), "+v"(P[0][2]), "+v"(P[0][3]),
          "+v"(P[1][0]), "+v"(P[1][1]), "+v"(P[1][2]), "+v"(P[1][3]),
          "+v"(P[2][0]), "+v"(P[2][1]), "+v"(P[2][2]), "+v"(P[2][3]),
          "+v"(P[3][0]), "+v"(P[3][1]), "+v"(P[3][2]), "+v"(P[3][3]));

    // ---- phase 4: PV MFMA cluster (setprio'd) ----
    __builtin_amdgcn_s_setprio(1);
#pragma unroll
    for (int mt = 0; mt < 4; mt++) {
      union {
        unsigned u[4];
        short8 s;
      } cv;
      cv.u[0] = P[mt][0];  // F0: k-slots 0,1
      cv.u[1] = P[mt][1];  // F1: k-slots 2,3
      cv.u[2] = P[mt][2];  // F2: k-slots 4,5
      cv.u[3] = P[mt][3];  // F3: k-slots 6,7
      short8 pa = cv.s;
      o[mt][0] = __builtin_amdgcn_mfma_f32_16x16x32_bf16(pa, v0f, o[mt][0], 0, 0, 0);
      o[mt][1] = __builtin_amdgcn_mfma_f32_16x16x32_bf16(pa, v1f, o[mt][1], 0, 0, 0);
      lacc[mt] = __builtin_amdgcn_mfma_f32_16x16x32_bf16(pa, ones, lacc[mt], 0, 0, 0);
    }
    __builtin_amdgcn_s_setprio(0);
  }

#pragma unroll
  for (int mt = 0; mt < 4; mt++) {
#pragma unroll
    for (int r = 0; r < 4; r++) {
      float lv = __shfl(lacc[mt][r], lane & 48, 64);  // col 0 of this row-quad
      float inv = __builtin_amdgcn_rcpf(lv);
      size_t yb = ((size_t)b * T_ + t0 + mt * 16 + q * 4 + r) * DM + h * HD;
      Y[yb + i] = f2bf(o[mt][0][r] * inv);
      Y[yb + 16 + i] = f2bf(o[mt][1][r] * inv);
    }
  }
}

// ---------------- kernel 3: output GEMM, gathered A rows ----------------------
__global__ __launch_bounds__(256) void out_gemm(
    const short* __restrict__ Y, const short* __restrict__ WPb,
    const float* __restrict__ bp, const int* __restrict__ inv,
    float* __restrict__ out) {
  __shared__ __align__(16) char smem[3 * 16384];
  int tid = threadIdx.x;
  int lane = tid & 63, w = tid >> 6;
  int i = lane & 15, q = lane >> 4;
  int m0 = blockIdx.x * 128, n0 = blockIdx.y * 128;
  int wm = (w & 1) * 64, wn = (w >> 1) * 64;
  int csa = q ^ ((i >> 1) & 3);

  int iv0 = inv[m0 + (tid >> 2)];
  int iv1 = inv[m0 + 64 + (tid >> 2)];

  f32x4 zf = {0.f, 0.f, 0.f, 0.f};
  f32x4 acc[4][4];
#pragma unroll
  for (int mt = 0; mt < 4; mt++)
#pragma unroll
    for (int nt = 0; nt < 4; nt++) acc[mt][nt] = zf;

  auto stage = [&](int k, int s) {
#pragma unroll
    for (int p = 0; p < 2; p++) {
      int U = p * 256 + tid;
      int row = U >> 2, c = U & 3;
      int cs = c ^ ((row >> 1) & 3);
      int iv = p ? iv1 : iv0;
      gl_lds16(Y + (size_t)iv * DM + k * 32 + cs * 8, smem + s * 16384 + U * 16);
      gl_lds16(WPb + (size_t)(n0 + row) * DM + k * 32 + cs * 8,
               smem + s * 16384 + 8192 + U * 16);
    }
  };

  stage(0, 0);
  stage(1, 1);
#pragma unroll
  for (int k = 0; k < 8; k++) {
    if (k == 7)
      asm volatile("s_waitcnt vmcnt(0) lgkmcnt(0)\ns_barrier" ::: "memory");
    else
      asm volatile("s_waitcnt vmcnt(4) lgkmcnt(0)\ns_barrier" ::: "memory");
    const short* Asb = (const short*)(smem + (k % 3) * 16384);
    const short* Bsb = Asb + 4096;
    short8 a[4], bfr[4];
#pragma unroll
    for (int mt = 0; mt < 4; mt++)
      a[mt] = *(const short8*)&Asb[(wm + mt * 16 + i) * 32 + csa * 8];
#pragma unroll
    for (int nt = 0; nt < 4; nt++)
      bfr[nt] = *(const short8*)&Bsb[(wn + nt * 16 + i) * 32 + csa * 8];
    if (k < 6) stage(k + 2, (k + 2) % 3);
#pragma unroll
    for (int mt = 0; mt < 4; mt++)
#pragma unroll
      for (int nt = 0; nt < 4; nt++)
        acc[mt][nt] = __builtin_amdgcn_mfma_f32_16x16x32_bf16(a[mt], bfr[nt], acc[mt][nt], 0, 0, 0);
  }

#pragma unroll
  for (int nt = 0; nt < 4; nt++) {
    int f = n0 + wn + nt * 16 + i;
    float bias = bp[f];
#pragma unroll
    for (int mt = 0; mt < 4; mt++) {
#pragma unroll
      for (int r = 0; r < 4; r++) {
        int row = m0 + wm + mt * 16 + q * 4 + r;
        out[(size_t)row * DM + f] = acc[mt][nt][r] + bias;
      }
    }
  }
}

// ---------------- launch ----------------
extern "C" void kernel_launch(void* const* d_in, const int* in_sizes, int n_in,
                              void* d_out, int out_size, void* d_ws, size_t ws_size,
                              hipStream_t stream) {
  const float* x = (const float*)d_in[0];
  const float* Wq = (const float*)d_in[1];
  const float* bq = (const float*)d_in[2];
  const float* Wk = (const float*)d_in[3];
  const float* bk = (const float*)d_in[4];
  const float* Wv = (const float*)d_in[5];
  const float* bv = (const float*)d_in[6];
  const float* Wp = (const float*)d_in[7];
  const float* bp = (const float*)d_in[8];
  const int* idx = (const int*)d_in[9];
  const int* batch = (const int*)d_in[10];
  const int* inv = (const int*)d_in[11];
  float* out = (float*)d_out;

  char* ws = (char*)d_ws;
  short* XP = (short*)(ws + 0);                            // 16,777,216 B
  short* WCAT = (short*)(ws + 16777216);                   //    393,216 B
  short* WPb = (short*)(ws + 17170432);                    //    131,072 B
  float* BCAT = (float*)(ws + 17301504);                   //      3,072 B
  unsigned short* QKVp = (unsigned short*)(ws + 17304576); // 50,331,648 B
  unsigned short* Yb = (unsigned short*)(ws + 67636224);   // 16,777,216 B
  // total ws use: 84,413,440 B

  pack_kernel<<<4224, 256, 0, stream>>>(x, Wq, Wk, Wv, Wp, bq, bk, bv, idx,
                                        XP, WCAT, WPb, BCAT);
  qkv_gemm<<<dim3(256, 6), 256, 0, stream>>>(XP, WCAT, BCAT, QKVp);
  attn_kernel<<<512, 512, 0, stream>>>(QKVp, batch, Yb);
  out_gemm<<<dim3(192, 2), 256, 0, stream>>>((const short*)Yb, WPb, bp, inv, out);
}

// Round 9
// 163.624 us; speedup vs baseline: 1.1625x; 1.1625x over previous
//
#include <hip/hip_runtime.h>

// RaggedAttention on MI355X — bf16 MFMA pipeline.
// WCAT bf16[768][256] ([f][c] = B^T input); QKVp bf16[32768][768]
//   (f<256: Q pre-scaled by log2e/sqrt(32); [256,512): K; [512,768): V)
// Y bf16[32768][256].
// MFMA 16x16x32_bf16 mappings (HW-verified per guide):
//   A-frag: lane holds A[m=lane&15][k=(lane>>4)*8+j]
//   B-frag: lane holds B[k=(lane>>4)*8+j][n=lane&15]
//   C/D   : lane reg r holds D[row=(lane>>4)*4+r][col=lane&15]
// r7: swapped QK^T + permlane swaps rebuild PV A-frag in-register (pscr gone).
// r10: half-block split REGRESSED (occupancy not the constraint).
// r12: phase-batched attn REGRESSED via scratch spills (WRITE 16->47MB, VGPR
//      forced to 64). Reverted to r11 attn body.
// r13 (this round): budget math shows pack+qkv+out+gaps ~= 127us vs attn 41.
// Fuse the x-gather + f32->bf16 cast INTO qkv's A-staging (reg-staged A:
// float4 loads -> f2bf -> ds_write_b128; B stays gl_lds16 DMA; per-stage
// vmem = 4 A-loads + 2 B-DMAs; vmcnt(6) drains B(k) at iter top, vmcnt(8)/
// vmcnt(2) drains A(k+1) before its LDS write). XP buffer deleted; pack is
// weights-only (grid 4224 -> 128).

typedef __attribute__((ext_vector_type(8))) short short8;
typedef __attribute__((ext_vector_type(4))) float f32x4;

#define N_TOTAL 24576
#define B_ 64
#define T_ 512
#define DM 256
#define NH 8
#define HD 32
#define F3 768

// log2(e)/sqrt(HD) — folded into Q at projection time
#define QSCALE 0.25503463f
#define VSP 530   // LDS V-tile row stride (shorts): dword-stride 265 = 9 mod 32

__device__ __forceinline__ unsigned short f2bf(float f) {
  unsigned int u = __float_as_uint(f);
  u += 0x7fffu + ((u >> 16) & 1u);   // RNE
  return (unsigned short)(u >> 16);
}

__device__ __forceinline__ void gl_lds16(const void* g, void* l) {
  __builtin_amdgcn_global_load_lds(
      (const __attribute__((address_space(1))) unsigned int*)g,
      (__attribute__((address_space(3))) unsigned int*)l, 16, 0, 0);
}

// ---------------- kernel 0: weight packing (bf16 cast) ------------------------
__global__ __launch_bounds__(256) void pack_kernel(
    const float* __restrict__ Wq, const float* __restrict__ Wk,
    const float* __restrict__ Wv, const float* __restrict__ Wp,
    const float* __restrict__ bq, const float* __restrict__ bk,
    const float* __restrict__ bv,
    short* __restrict__ WCAT, short* __restrict__ WPb,
    float* __restrict__ BCAT) {
  int gid = blockIdx.x * 256 + threadIdx.x;
  if (gid < 768)
    BCAT[gid] = (gid < 256) ? bq[gid] : (gid < 512 ? bk[gid - 256] : bv[gid - 512]);
  const float* src;
  short* dst;
  if (gid < 24576) {
    int f = gid >> 5, seg = gid & 31;
    const float* W = (f < 256) ? Wq : ((f < 512) ? Wk : Wv);
    src = W + (size_t)(f & 255) * DM + seg * 8;
    dst = WCAT + (size_t)gid * 8;
  } else {
    int u = gid - 24576;
    src = Wp + (size_t)u * 8;
    dst = WPb + (size_t)u * 8;
  }
  const float4* s4 = (const float4*)src;
  float4 a = s4[0], b = s4[1];
  short8 o;
  o[0] = (short)f2bf(a.x); o[1] = (short)f2bf(a.y);
  o[2] = (short)f2bf(a.z); o[3] = (short)f2bf(a.w);
  o[4] = (short)f2bf(b.x); o[5] = (short)f2bf(b.y);
  o[6] = (short)f2bf(b.z); o[7] = (short)f2bf(b.w);
  *(short8*)dst = o;
}

// ---------------- kernel 1: fused gather+cast QKV GEMM ------------------------
// M=32768 (packed slots, A rows gathered via idx from f32 x), N=768, K=256.
// 128x128 tile, 4 waves. A: reg-staged (float4 -> f2bf -> ds_write_b128);
// B: gl_lds16 DMA. 3 slabs. Per stage: 4 A-loads + 2 B-DMAs (vmem order:
// A then B, stages in order). Epilogue: line-friendly unified QKVp store.
__global__ __launch_bounds__(256) void qkv_gemm(
    const float* __restrict__ x, const int* __restrict__ idx,
    const short* __restrict__ WCAT, const float* __restrict__ BCAT,
    unsigned short* __restrict__ QKVp) {
  __shared__ __align__(16) char smem[3 * 16384];
  int tid = threadIdx.x;
  int lane = tid & 63, w = tid >> 6;
  int i = lane & 15, q = lane >> 4;
  int m0 = blockIdx.x * 128, n0 = blockIdx.y * 128;
  int wm = (w & 1) * 64, wn = (w >> 1) * 64;
  int csa = q ^ ((i >> 1) & 3);

  // this thread's two quarter-rows (U = tid and U = 256+tid)
  int row0 = tid >> 2, c = tid & 3;
  int row1 = 64 + row0;
  int cs0 = c ^ ((row0 >> 1) & 3);
  int cs1 = c ^ ((row1 >> 1) & 3);
  const float* ax0 = x + (size_t)idx[m0 + row0] * DM;
  const float* ax1 = x + (size_t)idx[m0 + row1] * DM;

  f32x4 zf = {0.f, 0.f, 0.f, 0.f};
  f32x4 acc[4][4];
#pragma unroll
  for (int mt = 0; mt < 4; mt++)
#pragma unroll
    for (int nt = 0; nt < 4; nt++) acc[mt][nt] = zf;

  float4 fa[2][2][2];  // [parity][p][half] — all indices compile-time

  auto issueA = [&](int k, int par) {
    fa[par][0][0] = *(const float4*)(ax0 + k * 32 + cs0 * 8);
    fa[par][0][1] = *(const float4*)(ax0 + k * 32 + cs0 * 8 + 4);
    fa[par][1][0] = *(const float4*)(ax1 + k * 32 + cs1 * 8);
    fa[par][1][1] = *(const float4*)(ax1 + k * 32 + cs1 * 8 + 4);
  };
  auto issueB = [&](int k, int s) {
    gl_lds16(WCAT + (size_t)(n0 + row0) * DM + k * 32 + cs0 * 8,
             smem + s * 16384 + 8192 + tid * 16);
    gl_lds16(WCAT + (size_t)(n0 + row1) * DM + k * 32 + cs1 * 8,
             smem + s * 16384 + 8192 + (256 + tid) * 16);
  };
  auto writeA = [&](int s, int par) {
    short8 o0, o1;
    float4 l0 = fa[par][0][0], h0 = fa[par][0][1];
    float4 l1 = fa[par][1][0], h1 = fa[par][1][1];
    o0[0] = (short)f2bf(l0.x); o0[1] = (short)f2bf(l0.y);
    o0[2] = (short)f2bf(l0.z); o0[3] = (short)f2bf(l0.w);
    o0[4] = (short)f2bf(h0.x); o0[5] = (short)f2bf(h0.y);
    o0[6] = (short)f2bf(h0.z); o0[7] = (short)f2bf(h0.w);
    o1[0] = (short)f2bf(l1.x); o1[1] = (short)f2bf(l1.y);
    o1[2] = (short)f2bf(l1.z); o1[3] = (short)f2bf(l1.w);
    o1[4] = (short)f2bf(h1.x); o1[5] = (short)f2bf(h1.y);
    o1[6] = (short)f2bf(h1.z); o1[7] = (short)f2bf(h1.w);
    *(short8*)(smem + s * 16384 + tid * 16) = o0;
    *(short8*)(smem + s * 16384 + (256 + tid) * 16) = o1;
  };

  // prologue: A0,B0,A1,B1 issued in order; drain A0 (vmcnt: 12 -> 8); write A0
  issueA(0, 0);
  issueB(0, 0);
  issueA(1, 1);
  issueB(1, 1);
  asm volatile("s_waitcnt vmcnt(8)" ::: "memory");
  writeA(0, 0);

#pragma unroll
  for (int k = 0; k < 8; k++) {
    // top: drain B(k) (outstanding: B(k)2 + A(k+1)4 + B(k+1)2 = 8 -> 6) and
    // our own A-writes; then barrier.
    if (k == 7)
      asm volatile("s_waitcnt vmcnt(0) lgkmcnt(0)\ns_barrier" ::: "memory");
    else
      asm volatile("s_waitcnt vmcnt(6) lgkmcnt(0)\ns_barrier" ::: "memory");
    const short* Asb = (const short*)(smem + (k % 3) * 16384);
    const short* Bsb = Asb + 4096;
    short8 a[4], bfr[4];
#pragma unroll
    for (int mt = 0; mt < 4; mt++)
      a[mt] = *(const short8*)&Asb[(wm + mt * 16 + i) * 32 + csa * 8];
#pragma unroll
    for (int nt = 0; nt < 4; nt++)
      bfr[nt] = *(const short8*)&Bsb[(wn + nt * 16 + i) * 32 + csa * 8];
    if (k < 6) {
      issueA(k + 2, k & 1);
      issueB(k + 2, (k + 2) % 3);
    }
#pragma unroll
    for (int mt = 0; mt < 4; mt++)
#pragma unroll
      for (int nt = 0; nt < 4; nt++)
        acc[mt][nt] = __builtin_amdgcn_mfma_f32_16x16x32_bf16(a[mt], bfr[nt], acc[mt][nt], 0, 0, 0);
    if (k < 7) {
      // drain A(k+1): k<6 outstanding A(k+1)4+B(k+1)2+A(k+2)4+B(k+2)2=12 -> 8;
      // k==6 outstanding A(7)4+B(7)2=6 -> 2.
      if (k < 6)
        asm volatile("s_waitcnt vmcnt(8)" ::: "memory");
      else
        asm volatile("s_waitcnt vmcnt(2)" ::: "memory");
      writeA((k + 1) % 3, (k + 1) & 1);
    }
  }

  // epilogue: bias (+QSCALE for Q-part) and store to unified QKVp[token][f].
  float scale = (n0 < 256) ? QSCALE : 1.0f;
#pragma unroll
  for (int nt = 0; nt < 4; nt++) {
    int f = n0 + wn + nt * 16 + i;
    float bias = BCAT[f];
#pragma unroll
    for (int mt = 0; mt < 4; mt++) {
#pragma unroll
      for (int r = 0; r < 4; r++) {
        int token = m0 + wm + mt * 16 + q * 4 + r;
        QKVp[(size_t)token * F3 + f] = f2bf((acc[mt][nt][r] + bias) * scale);
      }
    }
  }
}

// ---------------- kernel 2: attention (r11 body, proven) ----------------------
// block = 8 waves (512 thr); wave = 64 t-rows of one (b,h); s-step 32.
// Grid 512 = one block per (b,h): 2 blocks/CU, no tail; h = bx>>6, b = bx&63.
// Swapped QK^T: st = mfma(A=K-tile, B=qf) -> lane holds S^T[s=q*4+r+16tt][t=i].
// Mask+exp in-reg, pack bf16 pairs, hazard-padded permlane swap pair rebuilds
// the PV A-frag (P[t=i][s=q*8+j]) with zero LDS traffic.
__global__ __launch_bounds__(512, 4) void attn_kernel(
    const unsigned short* __restrict__ QKVp, const int* __restrict__ batch,
    unsigned short* __restrict__ Y) {
  __shared__ __align__(16) short Vl[HD * VSP];      // 33,920 B
  __shared__ int sbat[T_];                          //  2,048 B
  int tid = threadIdx.x, w = tid >> 6, lane = tid & 63;
  int i = lane & 15, q = lane >> 4;
  int bx = blockIdx.x;
  int h = bx >> 6, b = bx & 63;   // all 8 heads of a batch share an XCD
  int t0 = w * 64;
  const unsigned short* Tok = QKVp + (size_t)b * T_ * F3;  // this batch's rows

  sbat[tid] = batch[b * T_ + tid];

  // V transpose: global [t][d] (64B head-aligned lines) -> LDS Vl[d][s]
  {
    int seg = tid & 3, sb = tid >> 2;   // seg: 8-d chunk; sb: s base (0..127)
#pragma unroll
    for (int l = 0; l < 4; l++) {
      int s = sb + l * 128;
      short8 v = *(const short8*)&Tok[(size_t)s * F3 + 512 + h * HD + seg * 8];
#pragma unroll
      for (int j = 0; j < 8; j++) Vl[(seg * 8 + j) * VSP + s] = v[j];
    }
  }
  __syncthreads();

  short8 qf[4];
  int btm[4];
#pragma unroll
  for (int mt = 0; mt < 4; mt++)
    qf[mt] = *(const short8*)&Tok[(size_t)(t0 + mt * 16 + i) * F3 + h * HD + q * 8];
#pragma unroll
  for (int mt = 0; mt < 4; mt++) btm[mt] = sbat[t0 + mt * 16 + i];

  // ones B-fragment: B[k][n] = (n==0) ? 1.0bf16 : 0
  unsigned short ob = (i == 0) ? (unsigned short)0x3F80 : (unsigned short)0;
  short8 ones = {(short)ob, (short)ob, (short)ob, (short)ob,
                 (short)ob, (short)ob, (short)ob, (short)ob};

  f32x4 zf = {0.f, 0.f, 0.f, 0.f};
  f32x4 o[4][2], lacc[4];
#pragma unroll
  for (int mt = 0; mt < 4; mt++) {
    o[mt][0] = zf; o[mt][1] = zf; lacc[mt] = zf;
  }

  // K A-frag: lane (i,q) holds K[s0 + i (+16 for tile1)][d = q*8..q*8+7]
  const unsigned short* Kb = Tok + 256 + h * HD + q * 8;
  short8 k0f = *(const short8*)&Kb[(size_t)(i)*F3];
  short8 k1f = *(const short8*)&Kb[(size_t)(16 + i) * F3];

  for (int s0 = 0; s0 < T_; s0 += 32) {
    short8 ck0 = k0f, ck1 = k1f;
    if (s0 + 32 < T_) {
      k0f = *(const short8*)&Kb[(size_t)(s0 + 32 + i) * F3];
      k1f = *(const short8*)&Kb[(size_t)(s0 + 48 + i) * F3];
    }
    int4 bs0 = *(const int4*)&sbat[s0 + q * 4];        // batch of s = s0+q*4+r
    int4 bs1 = *(const int4*)&sbat[s0 + 16 + q * 4];   // batch of s = s0+16+q*4+r
    short8 v0f = *(const short8*)&Vl[i * VSP + s0 + q * 8];
    short8 v1f = *(const short8*)&Vl[(16 + i) * VSP + s0 + q * 8];
#pragma unroll
    for (int mt = 0; mt < 4; mt++) {
      // S^T tiles: D[row = s-local = q*4+r][col = t-local = i]
      f32x4 st0 = __builtin_amdgcn_mfma_f32_16x16x32_bf16(ck0, qf[mt], zf, 0, 0, 0);
      f32x4 st1 = __builtin_amdgcn_mfma_f32_16x16x32_bf16(ck1, qf[mt], zf, 0, 0, 0);
      int bm = btm[mt];
      float e00 = __builtin_amdgcn_exp2f((bs0.x == bm) ? -1e9f : st0[0]);
      float e01 = __builtin_amdgcn_exp2f((bs0.y == bm) ? -1e9f : st0[1]);
      float e02 = __builtin_amdgcn_exp2f((bs0.z == bm) ? -1e9f : st0[2]);
      float e03 = __builtin_amdgcn_exp2f((bs0.w == bm) ? -1e9f : st0[3]);
      float e10 = __builtin_amdgcn_exp2f((bs1.x == bm) ? -1e9f : st1[0]);
      float e11 = __builtin_amdgcn_exp2f((bs1.y == bm) ? -1e9f : st1[1]);
      float e12 = __builtin_amdgcn_exp2f((bs1.z == bm) ? -1e9f : st1[2]);
      float e13 = __builtin_amdgcn_exp2f((bs1.w == bm) ? -1e9f : st1[3]);
      // pack bf16 pairs along s (truncation, same as prior perm trick)
      unsigned A0 = __builtin_amdgcn_perm(__float_as_uint(e01), __float_as_uint(e00), 0x07060302u);
      unsigned A1 = __builtin_amdgcn_perm(__float_as_uint(e03), __float_as_uint(e02), 0x07060302u);
      unsigned B0 = __builtin_amdgcn_perm(__float_as_uint(e11), __float_as_uint(e10), 0x07060302u);
      unsigned B1 = __builtin_amdgcn_perm(__float_as_uint(e13), __float_as_uint(e12), 0x07060302u);
      // redistribute among lanes {i, i+16, i+32, i+48}:
      // swap32(A,B) -> A=[A.lo|B.lo], B=[A.hi|B.hi]
      // swap16(A,B) -> A=[A.r0,B.r0,A.r2,B.r2], B=[A.r1,B.r1,A.r3,B.r3]
      // ONE asm block; s_nop padding covers VALU->permlane, permlane->permlane
      // and permlane->MFMA manual wait states (hazard recognizer is blind
      // inside INLINEASM).
      asm volatile(
          "s_nop 1\n\t"
          "v_permlane32_swap_b32 %0, %2\n\t"
          "v_permlane32_swap_b32 %1, %3\n\t"
          "s_nop 1\n\t"
          "v_permlane16_swap_b32 %0, %2\n\t"
          "v_permlane16_swap_b32 %1, %3\n\t"
          "s_nop 1"
          : "+v"(A0), "+v"(A1), "+v"(B0), "+v"(B1));
      union {
        unsigned u[4];
        short8 s;
      } cv;
      cv.u[0] = A0;  // F0: k-slots 0,1
      cv.u[1] = A1;  // F1: k-slots 2,3
      cv.u[2] = B0;  // F2: k-slots 4,5
      cv.u[3] = B1;  // F3: k-slots 6,7
      short8 pa = cv.s;
      o[mt][0] = __builtin_amdgcn_mfma_f32_16x16x32_bf16(pa, v0f, o[mt][0], 0, 0, 0);
      o[mt][1] = __builtin_amdgcn_mfma_f32_16x16x32_bf16(pa, v1f, o[mt][1], 0, 0, 0);
      lacc[mt] = __builtin_amdgcn_mfma_f32_16x16x32_bf16(pa, ones, lacc[mt], 0, 0, 0);
    }
  }

#pragma unroll
  for (int mt = 0; mt < 4; mt++) {
#pragma unroll
    for (int r = 0; r < 4; r++) {
      float lv = __shfl(lacc[mt][r], lane & 48, 64);  // col 0 of this row-quad
      float inv = __builtin_amdgcn_rcpf(lv);
      size_t yb = ((size_t)b * T_ + t0 + mt * 16 + q * 4 + r) * DM + h * HD;
      Y[yb + i] = f2bf(o[mt][0][r] * inv);
      Y[yb + 16 + i] = f2bf(o[mt][1][r] * inv);
    }
  }
}

// ---------------- kernel 3: output GEMM, gathered A rows ----------------------
__global__ __launch_bounds__(256) void out_gemm(
    const short* __restrict__ Y, const short* __restrict__ WPb,
    const float* __restrict__ bp, const int* __restrict__ inv,
    float* __restrict__ out) {
  __shared__ __align__(16) char smem[3 * 16384];
  int tid = threadIdx.x;
  int lane = tid & 63, w = tid >> 6;
  int i = lane & 15, q = lane >> 4;
  int m0 = blockIdx.x * 128, n0 = blockIdx.y * 128;
  int wm = (w & 1) * 64, wn = (w >> 1) * 64;
  int csa = q ^ ((i >> 1) & 3);

  int iv0 = inv[m0 + (tid >> 2)];
  int iv1 = inv[m0 + 64 + (tid >> 2)];

  f32x4 zf = {0.f, 0.f, 0.f, 0.f};
  f32x4 acc[4][4];
#pragma unroll
  for (int mt = 0; mt < 4; mt++)
#pragma unroll
    for (int nt = 0; nt < 4; nt++) acc[mt][nt] = zf;

  auto stage = [&](int k, int s) {
#pragma unroll
    for (int p = 0; p < 2; p++) {
      int U = p * 256 + tid;
      int row = U >> 2, c = U & 3;
      int cs = c ^ ((row >> 1) & 3);
      int iv = p ? iv1 : iv0;
      gl_lds16(Y + (size_t)iv * DM + k * 32 + cs * 8, smem + s * 16384 + U * 16);
      gl_lds16(WPb + (size_t)(n0 + row) * DM + k * 32 + cs * 8,
               smem + s * 16384 + 8192 + U * 16);
    }
  };

  stage(0, 0);
  stage(1, 1);
#pragma unroll
  for (int k = 0; k < 8; k++) {
    if (k == 7)
      asm volatile("s_waitcnt vmcnt(0) lgkmcnt(0)\ns_barrier" ::: "memory");
    else
      asm volatile("s_waitcnt vmcnt(4) lgkmcnt(0)\ns_barrier" ::: "memory");
    const short* Asb = (const short*)(smem + (k % 3) * 16384);
    const short* Bsb = Asb + 4096;
    short8 a[4], bfr[4];
#pragma unroll
    for (int mt = 0; mt < 4; mt++)
      a[mt] = *(const short8*)&Asb[(wm + mt * 16 + i) * 32 + csa * 8];
#pragma unroll
    for (int nt = 0; nt < 4; nt++)
      bfr[nt] = *(const short8*)&Bsb[(wn + nt * 16 + i) * 32 + csa * 8];
    if (k < 6) stage(k + 2, (k + 2) % 3);
#pragma unroll
    for (int mt = 0; mt < 4; mt++)
#pragma unroll
      for (int nt = 0; nt < 4; nt++)
        acc[mt][nt] = __builtin_amdgcn_mfma_f32_16x16x32_bf16(a[mt], bfr[nt], acc[mt][nt], 0, 0, 0);
  }

#pragma unroll
  for (int nt = 0; nt < 4; nt++) {
    int f = n0 + wn + nt * 16 + i;
    float bias = bp[f];
#pragma unroll
    for (int mt = 0; mt < 4; mt++) {
#pragma unroll
      for (int r = 0; r < 4; r++) {
        int row = m0 + wm + mt * 16 + q * 4 + r;
        out[(size_t)row * DM + f] = acc[mt][nt][r] + bias;
      }
    }
  }
}

// ---------------- launch ----------------
extern "C" void kernel_launch(void* const* d_in, const int* in_sizes, int n_in,
                              void* d_out, int out_size, void* d_ws, size_t ws_size,
                              hipStream_t stream) {
  const float* x = (const float*)d_in[0];
  const float* Wq = (const float*)d_in[1];
  const float* bq = (const float*)d_in[2];
  const float* Wk = (const float*)d_in[3];
  const float* bk = (const float*)d_in[4];
  const float* Wv = (const float*)d_in[5];
  const float* bv = (const float*)d_in[6];
  const float* Wp = (const float*)d_in[7];
  const float* bp = (const float*)d_in[8];
  const int* idx = (const int*)d_in[9];
  const int* batch = (const int*)d_in[10];
  const int* inv = (const int*)d_in[11];
  float* out = (float*)d_out;

  char* ws = (char*)d_ws;
  short* WCAT = (short*)(ws + 0);                          //    393,216 B
  short* WPb = (short*)(ws + 524288);                      //    131,072 B
  float* BCAT = (float*)(ws + 1048576);                    //      3,072 B
  unsigned short* QKVp = (unsigned short*)(ws + 2097152);  // 50,331,648 B
  unsigned short* Yb = (unsigned short*)(ws + 52428800);   // 16,777,216 B
  // total ws use: 69,206,016 B

  pack_kernel<<<128, 256, 0, stream>>>(Wq, Wk, Wv, Wp, bq, bk, bv,
                                       WCAT, WPb, BCAT);
  qkv_gemm<<<dim3(256, 6), 256, 0, stream>>>(x, idx, WCAT, BCAT, QKVp);
  attn_kernel<<<512, 512, 0, stream>>>(QKVp, batch, Yb);
  out_gemm<<<dim3(192, 2), 256, 0, stream>>>((const short*)Yb, WPb, bp, inv, out);
}